// Round 2
// baseline (412.041 us; speedup 1.0000x reference)
//
#include <hip/hip_runtime.h>
#include <hip/hip_bf16.h>

// CRF loss, round 4.
// logZ = log((E_0 * ... * E_511)[START][END]), E_t = exp(M_t) elementwise.
//
// K1: 2048 chunk chains (1 wave each, 16 matrices). REVERSED chain: state
//   B = suffix product P_t = E_t * P_{t+1}, t = 15..0, identity-initialized.
//   A-operand = UNtransposed E_t -> 9 coalesced float4 loads per lane per t
//   (round-2 kernel did 36 scalar transposed loads). D layout (row=quad*4+r,
//   col=lane&15) == B layout (k=quad*4+j, n=col) -> D feeds next B, no LDS.
//   2^-7 rescale folded into exp argument (exp(x - 7 ln2)) for rounds t=14..0
//   ONLY; first round (t=15, B=I) uses unbiased exp. 15 biased rounds ->
//   chunk scale 2^-105, identical to the round-2-validated scheme.
//   (Round-3 lesson: biasing all 16 rounds gave 2^-112 chunks; K2's fixed
//   2^5 rescale then underflowed the product tree to 0 -> log(0) = -inf.)
//   Store H^T row-major as bf16x4: out[n][k] = G[k][n], same bytes as round 2.
// K2: identical to round-2-validated version: 1 block (4 waves)/batch; each
//   wave folds 8 H's (7 multiplies, x32 rescale), wave0 combines 4 results
//   via LDS; logZ = log(v) + (32*105 - 31*5)*ln2.
// K3: mean.

#define B_N 64
#define S_N 512
#define T_N 48
#define TT_N 2304
#define START_TAG 46
#define END_TAG 47
#define CHUNK_L 16
#define CPB 32
#define N_CHUNKS 2048
#define LN2F 0.6931471805599453f
#define EXP_BIAS 4.852030263919617f   /* 7 * ln2 */

typedef __bf16 bf16x4 __attribute__((ext_vector_type(4)));
typedef short short4v __attribute__((ext_vector_type(4)));
typedef float f32x4 __attribute__((ext_vector_type(4)));

static __device__ __forceinline__ f32x4 mfma16(bf16x4 a, bf16x4 b, f32x4 c) {
#if __has_builtin(__builtin_amdgcn_mfma_f32_16x16x16bf16_1k)
  return __builtin_amdgcn_mfma_f32_16x16x16bf16_1k(
      __builtin_bit_cast(short4v, a), __builtin_bit_cast(short4v, b), c, 0, 0, 0);
#else
  f32x4 d;
  asm("v_mfma_f32_16x16x16_bf16 %0, %1, %2, %3"
      : "=v"(d) : "v"(a), "v"(b), "v"(c));
  return d;
#endif
}

// ---------------- K1 ----------------
__global__ __launch_bounds__(256, 2) void crf_k1(const float* __restrict__ tr,
                                                 __bf16* __restrict__ wsH) {
  const int w = threadIdx.x >> 6, lane = threadIdx.x & 63;
  const int col = lane & 15, quad = lane >> 4;
  const int g = blockIdx.x * 4 + w;                 // chunk id; covers s = g*16 .. g*16+15
  const float* __restrict__ base = tr + (size_t)g * (CHUNK_L * TT_N);

  // state B = identity (exact in bf16)
  bf16x4 bfr[3][3];                                 // [kb][nt]
#pragma unroll
  for (int kb = 0; kb < 3; ++kb)
#pragma unroll
    for (int nt = 0; nt < 3; ++nt)
#pragma unroll
      for (int j = 0; j < 4; ++j)
        bfr[kb][nt][j] = (kb == nt && (quad * 4 + j) == col) ? (__bf16)1.0f : (__bf16)0.0f;

  // prefetch raw M_15 in A-layout (UNtransposed): A[m][k] = M[m][k], k contiguous
  f32x4 st[3][3];                                   // [mt][kt]
  {
    const float* nb = base + 15 * TT_N;
#pragma unroll
    for (int mt = 0; mt < 3; ++mt)
#pragma unroll
      for (int kt = 0; kt < 3; ++kt)
        st[mt][kt] = *(const f32x4*)(nb + (size_t)((mt * 16 + col) * T_N + kt * 16 + quad * 4));
  }

  f32x4 acc[3][3];
  for (int t = CHUNK_L - 1; t >= 0; --t) {
    // rounds t=14..0: A = exp(M_t - 7 ln2) = E_t * 2^-7 (rescale folded in).
    // round t=15 (B = I): unbiased, A = E_15. Total chunk scale = 2^-105.
    const float bias = (t == CHUNK_L - 1) ? 0.0f : EXP_BIAS;
    bf16x4 a[3][3];
#pragma unroll
    for (int mt = 0; mt < 3; ++mt)
#pragma unroll
      for (int kt = 0; kt < 3; ++kt)
#pragma unroll
        for (int j = 0; j < 4; ++j)
          a[mt][kt][j] = (__bf16)__expf(st[mt][kt][j] - bias);

    if (t > 0) {
      const float* nb = base + (size_t)(t - 1) * TT_N;
#pragma unroll
      for (int mt = 0; mt < 3; ++mt)
#pragma unroll
        for (int kt = 0; kt < 3; ++kt)
          st[mt][kt] = *(const f32x4*)(nb + (size_t)((mt * 16 + col) * T_N + kt * 16 + quad * 4));
    }

#pragma unroll
    for (int mt = 0; mt < 3; ++mt)
#pragma unroll
      for (int nt = 0; nt < 3; ++nt) {
        f32x4 c = {0.f, 0.f, 0.f, 0.f};
        c = mfma16(a[mt][0], bfr[0][nt], c);
        c = mfma16(a[mt][1], bfr[1][nt], c);
        c = mfma16(a[mt][2], bfr[2][nt], c);
        acc[mt][nt] = c;
      }
    // D -> next B (row index becomes k index); bare cvt, scale already in A
#pragma unroll
    for (int mt = 0; mt < 3; ++mt)
#pragma unroll
      for (int nt = 0; nt < 3; ++nt)
#pragma unroll
        for (int r = 0; r < 4; ++r)
          bfr[mt][nt][r] = (__bf16)acc[mt][nt][r];
  }

  // final B[k][n] = G[k][n] * 2^-105; store H = G^T row-major:
  // out[n*48 + k], k = kb*16 + quad*4 + j is j-contiguous -> bf16x4 stores
  __bf16* out = wsH + (size_t)g * TT_N;
#pragma unroll
  for (int kb = 0; kb < 3; ++kb)
#pragma unroll
    for (int nt = 0; nt < 3; ++nt)
      *(bf16x4*)(out + (size_t)((nt * 16 + col) * T_N + kb * 16 + quad * 4)) = bfr[kb][nt];
}

// ---------------- K2 ----------------
#define LDS_RS 52
__global__ __launch_bounds__(256, 2) void crf_k2(const float* __restrict__ tr,
                                                 const int* __restrict__ tgt,
                                                 const __bf16* __restrict__ wsH,
                                                 float* __restrict__ wsLoss) {
  const int b = blockIdx.x;
  const int tid = threadIdx.x;
  const int w = tid >> 6, lane = tid & 63;
  const int col = lane & 15, quad = lane >> 4;

  __shared__ __align__(16) __bf16 Sl[3][T_N * LDS_RS];
  __shared__ float red[4];

  // ---- target score (all 4 waves) ----
  float ts = 0.f;
  for (int s = tid; s < S_N; s += 256) {
    const int tg = tgt[b * S_N + s];
    const int pv = (s == 0) ? START_TAG : tgt[b * S_N + s - 1];
    ts += tr[(size_t)(b * S_N + s) * TT_N + pv * T_N + tg];
  }
#pragma unroll
  for (int s2 = 1; s2 < 64; s2 <<= 1) ts += __shfl_xor(ts, s2);
  if (lane == 0) red[w] = ts;

  // ---- wave-level product of 8 chunk matrices: S_w = (G_{8w}..G_{8w+7})^T * scale ----
  const __bf16* hb = wsH + (size_t)(b * CPB + w * 8) * TT_N;
  bf16x4 bfr[3][3];                                 // state as B-frags, init = H_{first}
#pragma unroll
  for (int kb = 0; kb < 3; ++kb)
#pragma unroll
    for (int nt = 0; nt < 3; ++nt)
#pragma unroll
      for (int j = 0; j < 4; ++j)
        bfr[kb][nt][j] = hb[(kb * 16 + quad * 4 + j) * T_N + nt * 16 + col];

  f32x4 acc[3][3];
  for (int c = 1; c < 8; ++c) {
    const __bf16* hc = hb + (size_t)c * TT_N;
    bf16x4 a[3][3];                                 // A = H_c (row-major, contiguous k)
#pragma unroll
    for (int mt = 0; mt < 3; ++mt)
#pragma unroll
      for (int kt = 0; kt < 3; ++kt)
        a[mt][kt] = *(const bf16x4*)(hc + (mt * 16 + col) * T_N + kt * 16 + quad * 4);
#pragma unroll
    for (int mt = 0; mt < 3; ++mt)
#pragma unroll
      for (int nt = 0; nt < 3; ++nt) {
        f32x4 c4 = {0.f, 0.f, 0.f, 0.f};
        c4 = mfma16(a[mt][0], bfr[0][nt], c4);
        c4 = mfma16(a[mt][1], bfr[1][nt], c4);
        c4 = mfma16(a[mt][2], bfr[2][nt], c4);
        acc[mt][nt] = c4;
      }
#pragma unroll
    for (int mt = 0; mt < 3; ++mt)
#pragma unroll
      for (int nt = 0; nt < 3; ++nt)
#pragma unroll
        for (int r = 0; r < 4; ++r)
          bfr[mt][nt][r] = (__bf16)(acc[mt][nt][r] * 32.0f);   // 2^5 per multiply
  }

  // waves 1..3 publish S_w to LDS (row-major, stride 52)
  if (w > 0) {
    __bf16* dst = &Sl[w - 1][0];
#pragma unroll
    for (int kb = 0; kb < 3; ++kb)
#pragma unroll
      for (int nt = 0; nt < 3; ++nt)
#pragma unroll
        for (int j = 0; j < 4; ++j)
          dst[(kb * 16 + quad * 4 + j) * LDS_RS + nt * 16 + col] = bfr[kb][nt][j];
  }
  __syncthreads();

  // ---- wave 0: T^T = S_3 * S_2 * S_1 * S_0 ----
  if (w == 0) {
    for (int m = 0; m < 3; ++m) {
      const __bf16* src = &Sl[m][0];
      bf16x4 a[3][3];
#pragma unroll
      for (int mt = 0; mt < 3; ++mt)
#pragma unroll
        for (int kt = 0; kt < 3; ++kt)
          a[mt][kt] = *(const bf16x4*)(src + (mt * 16 + col) * LDS_RS + kt * 16 + quad * 4);
#pragma unroll
      for (int mt = 0; mt < 3; ++mt)
#pragma unroll
        for (int nt = 0; nt < 3; ++nt) {
          f32x4 c4 = {0.f, 0.f, 0.f, 0.f};
          c4 = mfma16(a[mt][0], bfr[0][nt], c4);
          c4 = mfma16(a[mt][1], bfr[1][nt], c4);
          c4 = mfma16(a[mt][2], bfr[2][nt], c4);
          acc[mt][nt] = c4;
        }
#pragma unroll
      for (int mt = 0; mt < 3; ++mt)
#pragma unroll
        for (int nt = 0; nt < 3; ++nt)
#pragma unroll
          for (int r = 0; r < 4; ++r)
            bfr[mt][nt][r] = (__bf16)(acc[mt][nt][r] * 32.0f);
    }
    // T[START][END] = T^T[47][46] -> frag (2,2), local row 15 (quad=3,r=3), col 14 -> lane 62
    const float vv = __shfl(acc[2][2][3] * 32.0f, 62);
    if (lane == 0) {
      const float tsum = red[0] + red[1] + red[2] + red[3];
      // scale bookkeeping: 32 chunks * 2^-105, 31 K2-multiplies * 2^+5
      const float logZ = logf(vv) + (float)(CPB * 105 - 31 * 5) * LN2F;
      wsLoss[b] = -tsum + logZ;
    }
  }
}

// ---------------- K3 ----------------
__global__ void crf_k3(const float* __restrict__ wsLoss, float* __restrict__ out) {
  float x = wsLoss[threadIdx.x];
#pragma unroll
  for (int s = 1; s < 64; s <<= 1) x += __shfl_xor(x, s);
  if (threadIdx.x == 0) out[0] = x * (1.0f / 64.0f);
}

extern "C" void kernel_launch(void* const* d_in, const int* in_sizes, int n_in,
                              void* d_out, int out_size, void* d_ws, size_t ws_size,
                              hipStream_t stream) {
  const float* tr = (const float*)d_in[0];
  const int* tgt = (const int*)d_in[1];
  __bf16* wsH = (__bf16*)d_ws;                              // 2048 * 2304 bf16 = 9.4 MB
  float* wsLoss = (float*)((char*)d_ws + (size_t)N_CHUNKS * TT_N * sizeof(__bf16));

  crf_k1<<<N_CHUNKS / 4, 256, 0, stream>>>(tr, wsH);
  crf_k2<<<B_N, 256, 0, stream>>>(tr, tgt, wsH, wsLoss);
  crf_k3<<<1, 64, 0, stream>>>(wsLoss, (float*)d_out);
}